// Round 7
// baseline (8023.370 us; speedup 1.0000x reference)
//
#include <hip/hip_runtime.h>

#define LOWV (-10000.0f)
#define NBLK 512
typedef unsigned long long u64;

__device__ __forceinline__ float sigf(float x){ return 1.0f/(1.0f+expf(-x)); }
__device__ __forceinline__ unsigned fkey(float f){
    unsigned u = __float_as_uint(f);
    return (u & 0x80000000u) ? ~u : (u | 0x80000000u);
}
__device__ __forceinline__ float funkey(unsigned k){
    unsigned u = (k & 0x80000000u) ? (k ^ 0x80000000u) : ~k;
    return __uint_as_float(u);
}
__device__ __forceinline__ int   aload_i (const int* p){ return __hip_atomic_load(p, __ATOMIC_RELAXED, __HIP_MEMORY_SCOPE_AGENT); }
__device__ __forceinline__ float aload_f (const float* p){ return __hip_atomic_load(p, __ATOMIC_RELAXED, __HIP_MEMORY_SCOPE_AGENT); }
__device__ __forceinline__ u64   aload_u64(const u64* p){ return __hip_atomic_load(p, __ATOMIC_RELAXED, __HIP_MEMORY_SCOPE_AGENT); }
__device__ __forceinline__ void  astore_i(int* p, int v){ __hip_atomic_store(p, v, __ATOMIC_RELAXED, __HIP_MEMORY_SCOPE_AGENT); }
__device__ __forceinline__ void  astore_f(float* p, float v){ __hip_atomic_store(p, v, __ATOMIC_RELAXED, __HIP_MEMORY_SCOPE_AGENT); }

// ---------- transposes: WT[3072][640] = [Wh|Wpred]^T, WoutT[1024][512], WencT[512][1024] ----------
__global__ __launch_bounds__(256) void k_tr(const float* __restrict__ Wh, const float* __restrict__ Wpred,
        const float* __restrict__ Wout, const float* __restrict__ Wenc,
        float* __restrict__ WT, float* __restrict__ WoutT, float* __restrict__ WencT,
        int* __restrict__ cnt32){
    if (blockIdx.x == 0 && threadIdx.x < 32) cnt32[threadIdx.x*16] = 0;
    __shared__ float t[64][65];
    int b = blockIdx.x;
    const float* in; float* outp; int R, C, tr, tc, doff;
    if (b < 400)      { in=Wh;    outp=WT;    R=640;  C=2560; tr=b/40;        tc=b%40;        doff=0; }
    else if (b < 480) { b-=400; in=Wpred; outp=WT;    R=640;  C=512;  tr=b/8;  tc=b%8;  doff=2560; }
    else if (b < 608) { b-=480; in=Wout;  outp=WoutT; R=512;  C=1024; tr=b>>4; tc=b&15; doff=0; }
    else              { b-=608; in=Wenc;  outp=WencT; R=1024; C=512;  tr=b/8;  tc=b%8;  doff=0; }
    int tx = threadIdx.x & 63, ty0 = threadIdx.x >> 6;
    #pragma unroll
    for (int i = 0; i < 16; ++i){
        int row = i*4 + ty0;
        t[row][tx] = in[(size_t)(tr*64 + row)*C + tc*64 + tx];
    }
    __syncthreads();
    #pragma unroll
    for (int i = 0; i < 16; ++i){
        int row = i*4 + ty0;
        outp[(size_t)(doff + tc*64 + row)*R + tr*64 + tx] = t[tx][row];
    }
}

// ---------- EWi4[v*640+j] = float4 gates of E@Wi + bi + bh ----------
__global__ __launch_bounds__(256) void k_ewi(const float* __restrict__ E, const float* __restrict__ Wi,
        const float* __restrict__ bi, const float* __restrict__ bh, float4* __restrict__ EWi4){
    int tid = threadIdx.x, lane = tid & 63, wvv = tid >> 6;
    int vb = blockIdx.x / 10, jb = blockIdx.x % 10;   // 1280 blocks
    int j = jb*64 + lane;
    int v0 = vb*8 + wvv*2;
    float acc[2][4];
    #pragma unroll
    for (int i=0;i<2;++i)
        #pragma unroll
        for (int g=0;g<4;++g) acc[i][g] = 0.f;
    for (int k0 = 0; k0 < 512; k0 += 4){
        float ev[2][4];
        #pragma unroll
        for (int i=0;i<2;++i) *(float4*)ev[i] = *(const float4*)(E + (size_t)(v0+i)*512 + k0);
        #pragma unroll
        for (int kk=0;kk<4;++kk){
            const float* wr = Wi + (size_t)(k0+kk)*2560 + j;
            float w0 = wr[0], w1 = wr[640], w2 = wr[1280], w3 = wr[1920];
            #pragma unroll
            for (int i=0;i<2;++i){
                acc[i][0] += ev[i][kk]*w0; acc[i][1] += ev[i][kk]*w1;
                acc[i][2] += ev[i][kk]*w2; acc[i][3] += ev[i][kk]*w3;
            }
        }
    }
    float b0 = bi[j] + bh[j], b1 = bi[640+j] + bh[640+j];
    float b2 = bi[1280+j] + bh[1280+j], b3 = bi[1920+j] + bh[1920+j];
    #pragma unroll
    for (int i=0;i<2;++i)
        EWi4[(size_t)(v0+i)*640 + j] = make_float4(acc[i][0]+b0, acc[i][1]+b1, acc[i][2]+b2, acc[i][3]+b3);
}

// ---------- persistent decode kernel: 512 blocks x 512 threads, 2 blocks/CU ----------
__global__ __launch_bounds__(512, 4) void mega(
    const float* __restrict__ enc, const int* __restrict__ lens, const float* __restrict__ bj,
    const float* __restrict__ WT, const float* __restrict__ WoutT, const float* __restrict__ WencT,
    const float4* __restrict__ EWi4,
    float* __restrict__ hT, float* __restrict__ encPT, float* __restrict__ jointT, float* __restrict__ gT,
    u64* __restrict__ packed32, float* __restrict__ sumexp32,
    int* __restrict__ actA, int* __restrict__ encTA, int* __restrict__ nEmA,
    float* __restrict__ scoresA, int* __restrict__ tokF, int* __restrict__ advF,
    int* __restrict__ cnt32, float* __restrict__ out)
{
    __shared__ float sW[640*8];     // P1 weight slice, [k][8] padded (cols 0,1,2,_,3,4,5,_)
    __shared__ float sB[4*512];     // P2 Wout cols
    __shared__ float sWe[2*1024];   // enc-proj Wenc cols (blocks 160..415)
    __shared__ float sXP[12*128];   // P1 partials [kh*6+c][r]
    __shared__ float sP2[8*64];     // P2 partials
    __shared__ u64   sKX[256];
    __shared__ float sEX[256];
    __shared__ float sBJv[8];

    const int bid = blockIdx.x, tid = threadIdx.x, lane = tid & 63, wv = tid >> 6;
    int ep = 0;
    float creg = 0.f;

    auto gsync = [&](bool rel, bool inv){
        __syncthreads();
        ++ep;
        if (tid == 0){
            if (rel) __builtin_amdgcn_fence(__ATOMIC_RELEASE, "agent");
            __hip_atomic_fetch_add(&cnt32[(bid & 31)*16], 1, __ATOMIC_RELAXED, __HIP_MEMORY_SCOPE_AGENT);
        }
        if (wv == 0){
            int target = ep * NBLK;
            for (;;){
                int v = (lane < 32) ? __hip_atomic_load(&cnt32[lane*16], __ATOMIC_RELAXED, __HIP_MEMORY_SCOPE_AGENT) : 0;
                #pragma unroll
                for (int off = 32; off; off >>= 1) v += __shfl_xor(v, off, 64);
                if (v >= target) break;
                __builtin_amdgcn_s_sleep(2);
            }
        }
        __syncthreads();
        if (inv) __builtin_amdgcn_fence(__ATOMIC_ACQUIRE, "agent");
    };

    // ---- persistent weight staging ----
    for (int i = tid; i < 3840; i += 512){
        int c = i / 640, k = i - c*640;
        int cpad = (c < 3) ? c : c + 1;
        sW[k*8 + cpad] = WT[(size_t)(bid*6 + c)*640 + k];
    }
    {
        int C0 = (bid >> 1) * 4;
        for (int i = tid; i < 2048; i += 512){
            int cw = i >> 9, k = i & 511;
            sB[cw*512 + k] = WoutT[(size_t)(C0 + cw)*512 + k];
        }
    }
    if (bid >= 160 && bid < 416){
        int c0e = (bid - 160)*2;
        for (int i = tid; i < 2048; i += 512) sWe[i] = WencT[(size_t)c0e*1024 + i];
    }
    if (tid < 6){
        int col = bid*6 + tid;
        sBJv[tid] = (col >= 2560) ? bj[col - 2560] : 0.f;
    }
    __syncthreads();

    // ---- prologue ----
    for (int i = tid; i < 384; i += 512){
        int g = bid*384 + i;   // 512*384 = 196608 = 48*32*128
        packed32[g] = 0ull;
        sumexp32[g] = 0.f;
    }
    if (bid < 160){
        int j = bid*4 + (tid >> 7), r = tid & 127;
        float4 ew = EWi4[j];
        float c0v = sigf(ew.x)*tanhf(ew.z);
        creg = c0v;
        hT[(size_t)j*128 + r] = tanhf(c0v)*sigf(ew.w);
    } else if (bid < 416){
        int c0e = (bid - 160)*2;
        for (int r = wv; r < 128; r += 8){
            const float* er = enc + (size_t)r*160*1024;   // frame 0
            int k4 = lane*4;
            float a0 = 0.f, a1 = 0.f;
            #pragma unroll
            for (int i = 0; i < 4; ++i){
                int k = i*256 + k4;
                float4 ev = *(const float4*)(er + k);
                float4 wa = *(const float4*)(sWe + k);
                float4 wb = *(const float4*)(sWe + 1024 + k);
                a0 += ev.x*wa.x + ev.y*wa.y + ev.z*wa.z + ev.w*wa.w;
                a1 += ev.x*wb.x + ev.y*wb.y + ev.z*wb.z + ev.w*wb.w;
            }
            #pragma unroll
            for (int off = 32; off; off >>= 1){ a0 += __shfl_xor(a0, off, 64); a1 += __shfl_xor(a1, off, 64); }
            if (lane == 0){
                encPT[(size_t)c0e*128 + r]     = a0;
                encPT[(size_t)(c0e+1)*128 + r] = a1;
            }
        }
    } else if (bid >= 496){
        int q = bid - 496;
        if (tid < 8){
            int r = q*8 + tid;
            astore_i(&actA[r], 1); astore_i(&encTA[r], 0); astore_i(&nEmA[r], 0); astore_f(&scoresA[r], 0.f);
        }
    }
    gsync(true, true);   // B0

    for (int s = 0; s < 48; ++s){
        const int p = s & 1, w = 1 - p;
        const float* hp = hT + (size_t)p*81920;

        // ===== P1: flat GEMV (3072 cols = 2560 gates | 512 joint), 6 cols/block =====
        {
            int ct = wv & 1, rh = (wv >> 1) & 1, kh = wv >> 2;
            int r = rh*64 + lane;
            const float* hc = hp + r;
            const float* wbase = sW + ct*4;
            float a0 = 0.f, a1 = 0.f, a2 = 0.f;
            int k0 = kh*320;
            #pragma unroll 16
            for (int k = k0; k < k0 + 320; ++k){
                float h = hc[(size_t)k*128];
                float4 wq = *(const float4*)(wbase + k*8);
                a0 += h*wq.x; a1 += h*wq.y; a2 += h*wq.z;
            }
            sXP[(kh*6 + ct*3 + 0)*128 + r] = a0;
            sXP[(kh*6 + ct*3 + 1)*128 + r] = a1;
            sXP[(kh*6 + ct*3 + 2)*128 + r] = a2;
        }
        __syncthreads();
        for (int u = tid; u < 768; u += 512){
            int c = u >> 7, r = u & 127;
            float v = sXP[c*128 + r] + sXP[(6 + c)*128 + r];
            int col = bid*6 + c;
            if (col < 2560){
                gT[(size_t)col*128 + r] = v;
            } else {
                int cj = col - 2560;
                jointT[(size_t)cj*128 + r] = tanhf(v + encPT[(size_t)cj*128 + r] + sBJv[c]);
            }
        }
        gsync(true, false);   // B1

        // ===== P2: logits (4 cols x 64 rows / block) + 32-slot argmax/sumexp =====
        {
            int C0 = (bid >> 1) * 4, half = bid & 1;
            int cw = wv & 3, kh = wv >> 2;
            int r = half*64 + lane;
            const float* jc = jointT + r;
            const float* wr = sB + cw*512;
            float acc = 0.f;
            int k0 = kh*256;
            #pragma unroll 16
            for (int k = k0; k < k0 + 256; ++k)
                acc += jc[(size_t)k*128] * wr[k];
            sP2[(kh*4 + cw)*64 + lane] = acc;
            __syncthreads();
            if (tid < 256){
                int cw2 = tid >> 6, rr = tid & 63;
                int r2 = half*64 + rr;
                float lg = sP2[cw2*64 + rr] + sP2[(4 + cw2)*64 + rr];
                float ex = expf(lg);
                int col = C0 + cw2;
                bool force = aload_i(&nEmA[p*128 + r2]) >= 2;
                int idx; float va;
                if (col == 0){ idx = 1024; va = lg; }
                else { idx = col; va = force ? LOWV : lg; }
                sKX[cw2*64 + rr] = ((u64)fkey(va) << 32) | (unsigned)(2047 - idx);
                sEX[cw2*64 + rr] = ex;
            }
            __syncthreads();
            if (tid < 64){
                int r3 = half*64 + tid;
                u64 m = sKX[tid]; float es = sEX[tid];
                #pragma unroll
                for (int q = 1; q < 4; ++q){
                    u64 o = sKX[q*64 + tid]; if (o > m) m = o;
                    es += sEX[q*64 + tid];
                }
                int slot = bid >> 4;
                atomicMax(&packed32[((size_t)s*32 + slot)*128 + r3], m);
                atomicAdd(&sumexp32[((size_t)s*32 + slot)*128 + r3], es);
            }
        }
        gsync(false, false);  // B2

        // ===== P2b: 16 reducer blocks -> token + scalar state (coherent stores) =====
        if (bid >= 496 && tid < 256){
            int q = bid - 496;
            int ro = tid >> 5, sl = tid & 31;
            int r = q*8 + ro;
            u64 key = aload_u64(&packed32[((size_t)s*32 + sl)*128 + r]);
            float es = aload_f(&sumexp32[((size_t)s*32 + sl)*128 + r]);
            #pragma unroll
            for (int off = 1; off < 32; off <<= 1){
                unsigned lo = __shfl_xor((unsigned)key, off, 64);
                unsigned hi = __shfl_xor((unsigned)(key >> 32), off, 64);
                u64 o = ((u64)hi << 32) | lo;
                if (o > key) key = o;
                es += __shfl_xor(es, off, 64);
            }
            if (sl == 0){
                int act = aload_i(&actA[p*128 + r]);
                int et  = aload_i(&encTA[p*128 + r]);
                int ne  = aload_i(&nEmA[p*128 + r]);
                float sc = aload_f(&scoresA[p*128 + r]);
                int len = lens[r];
                int tok_out = 1024, act_n = 0, tokF_v = -1, advF_v = -1;
                if (act){
                    int tok = 2047 - (int)(unsigned)(key & 0xffffffffu);
                    float chosen = funkey((unsigned)(key >> 32));
                    float tlp = chosen - logf(es);
                    int isb = (tok == 1024);
                    sc += tlp;
                    if (isb){ et += 1; ne = 0; } else { ne += 1; tokF_v = tok; }
                    act_n = (et < len) ? 1 : 0;
                    tok_out = (act_n || isb) ? tok : 1024;
                    if (isb && act_n) advF_v = et;
                }
                astore_i(&actA[w*128 + r], act_n);
                astore_i(&encTA[w*128 + r], et);
                astore_i(&nEmA[w*128 + r], ne);
                astore_f(&scoresA[w*128 + r], sc);
                astore_i(&tokF[w*128 + r], tokF_v);
                astore_i(&advF[w*128 + r], advF_v);
                out[(size_t)r*48 + s] = (float)tok_out;
                if (s == 47) out[6144 + r] = sc;
            }
        }
        gsync(false, false);  // B3

        // ===== P3: pointwise LSTM (blocks<160) | lazy enc-proj (blocks 160..415) =====
        if (bid < 160){
            int j = bid*4 + (tid >> 7), r = tid & 127;
            int tf = aload_i(&tokF[w*128 + r]);
            float gi = gT[(size_t)j*128 + r];
            float gf = gT[(size_t)(640 + j)*128 + r];
            float gg = gT[(size_t)(1280 + j)*128 + r];
            float go = gT[(size_t)(1920 + j)*128 + r];
            float h2;
            if (tf >= 0){
                float4 ew = EWi4[(size_t)tf*640 + j];
                float cn = sigf(gf + ew.y)*creg + sigf(gi + ew.x)*tanhf(gg + ew.z);
                h2 = tanhf(cn)*sigf(go + ew.w);
                creg = cn;
            } else {
                h2 = hp[(size_t)j*128 + r];
            }
            hT[(size_t)w*81920 + (size_t)j*128 + r] = h2;
        } else if (bid < 416){
            int c0e = (bid - 160)*2;
            for (int r = wv; r < 128; r += 8){
                int t = aload_i(&advF[w*128 + r]);
                if (t < 0) continue;
                const float* er = enc + ((size_t)r*160 + t)*1024;
                int k4 = lane*4;
                float a0 = 0.f, a1 = 0.f;
                #pragma unroll
                for (int i = 0; i < 4; ++i){
                    int k = i*256 + k4;
                    float4 ev = *(const float4*)(er + k);
                    float4 wa = *(const float4*)(sWe + k);
                    float4 wb = *(const float4*)(sWe + 1024 + k);
                    a0 += ev.x*wa.x + ev.y*wa.y + ev.z*wa.z + ev.w*wa.w;
                    a1 += ev.x*wb.x + ev.y*wb.y + ev.z*wb.z + ev.w*wb.w;
                }
                #pragma unroll
                for (int off = 32; off; off >>= 1){ a0 += __shfl_xor(a0, off, 64); a1 += __shfl_xor(a1, off, 64); }
                if (lane == 0){
                    encPT[(size_t)c0e*128 + r]     = a0;
                    encPT[(size_t)(c0e+1)*128 + r] = a1;
                }
            }
        }
        gsync(true, true);    // B4
    }
}

extern "C" void kernel_launch(void* const* d_in, const int* in_sizes, int n_in,
                              void* d_out, int out_size, void* d_ws, size_t ws_size,
                              hipStream_t stream) {
    const float* enc   = (const float*)d_in[0];
    const int*   lens  = (const int*)  d_in[1];
    const float* E     = (const float*)d_in[3];
    const float* Wi    = (const float*)d_in[4];
    const float* Wh    = (const float*)d_in[5];
    const float* bi    = (const float*)d_in[6];
    const float* bh    = (const float*)d_in[7];
    const float* Wenc  = (const float*)d_in[8];
    const float* Wpred = (const float*)d_in[9];
    const float* bj    = (const float*)d_in[10];
    const float* Wout  = (const float*)d_in[11];
    float* out = (float*)d_out;

    char* base = (char*)d_ws;
    size_t off = 0;
    auto carve = [&](size_t bytes) -> void* {
        void* pp = base + off;
        off += (bytes + 255) & ~(size_t)255;
        return pp;
    };
    float*  WT    = (float*)carve((size_t)3072*640*4);     // 7.9 MB
    float*  WoutT = (float*)carve((size_t)1024*512*4);
    float*  WencT = (float*)carve((size_t)512*1024*4);
    float4* EWi4  = (float4*)carve((size_t)1024*640*16);   // 10.5 MB
    float*  hT    = (float*)carve((size_t)2*640*128*4);
    float*  encPT = (float*)carve((size_t)512*128*4);
    float*  jointT= (float*)carve((size_t)512*128*4);
    float*  gT    = (float*)carve((size_t)2560*128*4);     // 1.3 MB
    u64*    packed32 = (u64*)carve((size_t)48*32*128*8);   // 1.6 MB
    float*  sumexp32 = (float*)carve((size_t)48*32*128*4);
    int*    actA  = (int*)carve(2*128*4);
    int*    encTA = (int*)carve(2*128*4);
    int*    nEmA  = (int*)carve(2*128*4);
    float*  scoresA = (float*)carve(2*128*4);
    int*    tokF  = (int*)carve(2*128*4);
    int*    advF  = (int*)carve(2*128*4);
    int*    cnt32 = (int*)carve(32*16*4);
    (void)ws_size; (void)in_sizes; (void)n_in; (void)out_size;

    k_tr <<<736,  256, 0, stream>>>(Wh, Wpred, Wout, Wenc, WT, WoutT, WencT, cnt32);
    k_ewi<<<1280, 256, 0, stream>>>(E, Wi, bi, bh, EWi4);
    mega <<<NBLK, 512, 0, stream>>>(enc, lens, bj, WT, WoutT, WencT, EWi4,
                                    hT, encPT, jointT, gT, packed32, sumexp32,
                                    actA, encTA, nEmA, scoresA, tokF, advF, cnt32, out);
}

// Round 8
// 3889.342 us; speedup vs baseline: 2.0629x; 2.0629x over previous
//
#include <hip/hip_runtime.h>

#define LOWV (-10000.0f)
#define NBLK 256
typedef unsigned long long u64;

__device__ __forceinline__ float sigf(float x){ return 1.0f/(1.0f+expf(-x)); }
__device__ __forceinline__ unsigned fkey(float f){
    unsigned u = __float_as_uint(f);
    return (u & 0x80000000u) ? ~u : (u | 0x80000000u);
}
__device__ __forceinline__ float funkey(unsigned k){
    unsigned u = (k & 0x80000000u) ? (k ^ 0x80000000u) : ~k;
    return __uint_as_float(u);
}
__device__ __forceinline__ int   aload_i (const int* p){ return __hip_atomic_load(p, __ATOMIC_RELAXED, __HIP_MEMORY_SCOPE_AGENT); }
__device__ __forceinline__ float aload_f (const float* p){ return __hip_atomic_load(p, __ATOMIC_RELAXED, __HIP_MEMORY_SCOPE_AGENT); }
__device__ __forceinline__ u64   aload_u64(const u64* p){ return __hip_atomic_load(p, __ATOMIC_RELAXED, __HIP_MEMORY_SCOPE_AGENT); }
__device__ __forceinline__ void  astore_f(float* p, float v){ __hip_atomic_store(p, v, __ATOMIC_RELAXED, __HIP_MEMORY_SCOPE_AGENT); }
__device__ __forceinline__ void  astore_u64(u64* p, u64 v){ __hip_atomic_store(p, v, __ATOMIC_RELAXED, __HIP_MEMORY_SCOPE_AGENT); }

// ---------- transposes: WT[3072][640] = [Wh|Wpred]^T, WoutT[1024][512], WencT[512][1024] ----------
__global__ __launch_bounds__(256) void k_tr(const float* __restrict__ Wh, const float* __restrict__ Wpred,
        const float* __restrict__ Wout, const float* __restrict__ Wenc,
        float* __restrict__ WT, float* __restrict__ WoutT, float* __restrict__ WencT,
        int* __restrict__ cntZ){
    if (blockIdx.x == 0){ for (int i = threadIdx.x; i < 288; i += 256) cntZ[i] = 0; }
    __shared__ float t[64][65];
    int b = blockIdx.x;
    const float* in; float* outp; int R, C, tr, tc, doff;
    if (b < 400)      { in=Wh;    outp=WT;    R=640;  C=2560; tr=b/40;        tc=b%40;        doff=0; }
    else if (b < 480) { b-=400; in=Wpred; outp=WT;    R=640;  C=512;  tr=b/8;  tc=b%8;  doff=2560; }
    else if (b < 608) { b-=480; in=Wout;  outp=WoutT; R=512;  C=1024; tr=b>>4; tc=b&15; doff=0; }
    else              { b-=608; in=Wenc;  outp=WencT; R=1024; C=512;  tr=b/8;  tc=b%8;  doff=0; }
    int tx = threadIdx.x & 63, ty0 = threadIdx.x >> 6;
    #pragma unroll
    for (int i = 0; i < 16; ++i){
        int row = i*4 + ty0;
        t[row][tx] = in[(size_t)(tr*64 + row)*C + tc*64 + tx];
    }
    __syncthreads();
    #pragma unroll
    for (int i = 0; i < 16; ++i){
        int row = i*4 + ty0;
        outp[(size_t)(doff + tc*64 + row)*R + tr*64 + tx] = t[tx][row];
    }
}

// ---------- EWi4[v*640+j] = float4 gates of E@Wi + bi + bh ----------
__global__ __launch_bounds__(256) void k_ewi(const float* __restrict__ E, const float* __restrict__ Wi,
        const float* __restrict__ bi, const float* __restrict__ bh, float4* __restrict__ EWi4){
    int tid = threadIdx.x, lane = tid & 63, wvv = tid >> 6;
    int vb = blockIdx.x / 10, jb = blockIdx.x % 10;   // 1280 blocks
    int j = jb*64 + lane;
    int v0 = vb*8 + wvv*2;
    float acc[2][4];
    #pragma unroll
    for (int i=0;i<2;++i)
        #pragma unroll
        for (int g=0;g<4;++g) acc[i][g] = 0.f;
    for (int k0 = 0; k0 < 512; k0 += 4){
        float ev[2][4];
        #pragma unroll
        for (int i=0;i<2;++i) *(float4*)ev[i] = *(const float4*)(E + (size_t)(v0+i)*512 + k0);
        #pragma unroll
        for (int kk=0;kk<4;++kk){
            const float* wr = Wi + (size_t)(k0+kk)*2560 + j;
            float w0 = wr[0], w1 = wr[640], w2 = wr[1280], w3 = wr[1920];
            #pragma unroll
            for (int i=0;i<2;++i){
                acc[i][0] += ev[i][kk]*w0; acc[i][1] += ev[i][kk]*w1;
                acc[i][2] += ev[i][kk]*w2; acc[i][3] += ev[i][kk]*w3;
            }
        }
    }
    float b0 = bi[j] + bh[j], b1 = bi[640+j] + bh[640+j];
    float b2 = bi[1280+j] + bh[1280+j], b3 = bi[1920+j] + bh[1920+j];
    #pragma unroll
    for (int i=0;i<2;++i)
        EWi4[(size_t)(v0+i)*640 + j] = make_float4(acc[i][0]+b0, acc[i][1]+b1, acc[i][2]+b2, acc[i][3]+b3);
}

// ---------- persistent decode kernel: 256 blocks x 512 threads, 1 block/CU ----------
__global__ __launch_bounds__(512, 2) void mega(
    const float* __restrict__ enc, const int* __restrict__ lens, const float* __restrict__ bj,
    const float* __restrict__ WT, const float* __restrict__ WoutT, const float* __restrict__ WencT,
    const float4* __restrict__ EWi4,
    float* __restrict__ hT, float* __restrict__ encPT, float* __restrict__ jointT, float* __restrict__ gT,
    u64* __restrict__ packedP, float* __restrict__ sumexpP,
    int* __restrict__ cntZ, float* __restrict__ out)
{
    __shared__ float sW[12*640];                         // P1 weight slice [k][12]
    __shared__ __align__(16) float sXP[12*4*128];        // P1/P2 partials; P2 reduce aliases
    __shared__ float sB[8*512];                          // P2 Wout cols [k][8] (blocks 0..127)
    __shared__ float sWe[6*1024];                        // enc-proj cols (blocks 160..245)
    __shared__ float sBJ12[12];
    __shared__ int sAct[128], sEncT[128], sNEm[128], sLen[128];
    __shared__ int sTok[128], sUpd[128], sAdv[128];

    const int bid = blockIdx.x, tid = threadIdx.x, lane = tid & 63, wv = tid >> 6;
    int ep = 0;
    float creg = 0.f, scReg = 0.f;

    auto gsync = [&](bool rel, bool inv){
        __syncthreads();
        ++ep;
        if (tid == 0){
            if (rel) __builtin_amdgcn_fence(__ATOMIC_RELEASE, "agent");
            __hip_atomic_fetch_add(&cntZ[(bid & 15)*16], 1, __ATOMIC_RELAXED, __HIP_MEMORY_SCOPE_AGENT);
            if (bid < 16){
                while (__hip_atomic_load(&cntZ[bid*16], __ATOMIC_RELAXED, __HIP_MEMORY_SCOPE_AGENT) < ep*16)
                    __builtin_amdgcn_s_sleep(4);
                __hip_atomic_fetch_add(&cntZ[256], 1, __ATOMIC_RELAXED, __HIP_MEMORY_SCOPE_AGENT);
            }
            if (bid == 0){
                while (__hip_atomic_load(&cntZ[256], __ATOMIC_RELAXED, __HIP_MEMORY_SCOPE_AGENT) < ep*16)
                    __builtin_amdgcn_s_sleep(4);
                __hip_atomic_store(&cntZ[272], ep, __ATOMIC_RELAXED, __HIP_MEMORY_SCOPE_AGENT);
            } else {
                while (__hip_atomic_load(&cntZ[272], __ATOMIC_RELAXED, __HIP_MEMORY_SCOPE_AGENT) < ep)
                    __builtin_amdgcn_s_sleep(8);
            }
            if (inv) __builtin_amdgcn_fence(__ATOMIC_ACQUIRE, "agent");
        }
        __syncthreads();
    };

    // ---- weight staging ----
    for (int i = tid; i < 7680; i += 512){
        int c = i / 640, k = i - c*640;
        sW[k*12 + c] = WT[(size_t)(bid*12 + c)*640 + k];
    }
    if (bid < 128){
        for (int i = tid; i < 4096; i += 512){
            int k = i >> 3, c = i & 7;
            sB[k*8 + c] = WoutT[(size_t)(bid*8 + c)*512 + k];
        }
    }
    const int ec0 = (bid >= 160 && bid < 246) ? (bid-160)*6 : -1;
    const int nc  = (ec0 >= 0) ? ((512 - ec0) < 6 ? (512 - ec0) : 6) : 0;
    if (ec0 >= 0){
        for (int i = tid; i < 6144; i += 512){
            int cc = i >> 10, k = i & 1023;
            if (cc < nc) sWe[i] = WencT[(size_t)(ec0+cc)*1024 + k];
        }
    }
    if (tid < 12){
        int col = bid*12 + tid;
        sBJ12[tid] = (col >= 2560) ? bj[col - 2560] : 0.f;
    }
    if (tid < 128){
        sAct[tid] = 1; sEncT[tid] = 0; sNEm[tid] = 0; sLen[tid] = lens[tid];
    }
    __syncthreads();

    // ---- prologue ----
    for (int i = tid; i < 24; i += 512){
        int idx = bid*24 + i;                  // 256*24 = 6144 = 48*128
        astore_u64(&packedP[(size_t)idx*8], 0ull);
        astore_f(&sumexpP[(size_t)idx*16], 0.f);
    }
    if (bid < 160){
        int j = bid*4 + (tid >> 7), r = tid & 127;
        float4 e0 = EWi4[j];
        float c0v = sigf(e0.x)*tanhf(e0.z);
        creg = c0v;
        hT[(size_t)j*128 + r] = tanhf(c0v)*sigf(e0.w);
    }
    if (ec0 >= 0){
        for (int r = wv; r < 128; r += 8){
            const float* er = enc + (size_t)r*160*1024;   // frame 0
            float a[6] = {0,0,0,0,0,0};
            int k4 = lane*4;
            #pragma unroll
            for (int i = 0; i < 4; ++i){
                int k = i*256 + k4;
                float4 ev = *(const float4*)(er + k);
                for (int cc = 0; cc < nc; ++cc){
                    float4 w4 = *(const float4*)(sWe + cc*1024 + k);
                    a[cc] += ev.x*w4.x + ev.y*w4.y + ev.z*w4.z + ev.w*w4.w;
                }
            }
            for (int cc = 0; cc < nc; ++cc){
                #pragma unroll
                for (int off = 32; off; off >>= 1) a[cc] += __shfl_xor(a[cc], off, 64);
                if (lane == 0) encPT[(size_t)(ec0+cc)*128 + r] = a[cc];
            }
        }
    }
    gsync(true, true);   // B0

    for (int s = 0; s < 48; ++s){
        const int p = s & 1, w = 1 - p;
        const float* hp = hT + (size_t)p*81920;

        // ===== P1: flat GEMV 3072 cols (2560 gates | 512 joint), 12 cols/block =====
        {
            int ks = wv & 3, rh = wv >> 2;
            int r = rh*64 + lane;
            const float* hc = hp + r;
            float acc[12];
            #pragma unroll
            for (int c = 0; c < 12; ++c) acc[c] = 0.f;
            int k0 = ks*160;
            #pragma unroll 4
            for (int k = k0; k < k0 + 160; ++k){
                float h = hc[(size_t)k*128];
                const float* wk = sW + k*12;
                float4 wa = *(const float4*)(wk);
                float4 wb = *(const float4*)(wk + 4);
                float4 wc = *(const float4*)(wk + 8);
                acc[0] += h*wa.x; acc[1]  += h*wa.y; acc[2]  += h*wa.z; acc[3]  += h*wa.w;
                acc[4] += h*wb.x; acc[5]  += h*wb.y; acc[6]  += h*wb.z; acc[7]  += h*wb.w;
                acc[8] += h*wc.x; acc[9]  += h*wc.y; acc[10] += h*wc.z; acc[11] += h*wc.w;
            }
            #pragma unroll
            for (int c = 0; c < 12; ++c) sXP[c*512 + ks*128 + r] = acc[c];
        }
        __syncthreads();
        for (int u = tid; u < 1536; u += 512){
            int c = u >> 7, r = u & 127;
            const float* q = sXP + c*512 + r;
            float v = q[0] + q[128] + q[256] + q[384];
            int col = bid*12 + c;
            if (col < 2560){
                gT[(size_t)col*128 + r] = v;
            } else {
                int cj = col - 2560;
                jointT[(size_t)cj*128 + r] = tanhf(v + encPT[(size_t)cj*128 + r] + sBJ12[c]);
            }
        }
        gsync(true, true);   // B1

        // ===== P2: logits 8 cols/block (blocks 0..127) + per-row padded atomics =====
        if (bid < 128){
            int ks = wv & 3, rh = wv >> 2;
            int r = rh*64 + lane;
            const float* jc = jointT + r;
            float acc[8];
            #pragma unroll
            for (int c = 0; c < 8; ++c) acc[c] = 0.f;
            int k0 = ks*128;
            #pragma unroll 4
            for (int k = k0; k < k0 + 128; ++k){
                float jv = jc[(size_t)k*128];
                const float* wk = sB + k*8;
                float4 wa = *(const float4*)(wk);
                float4 wb = *(const float4*)(wk + 4);
                acc[0] += jv*wa.x; acc[1] += jv*wa.y; acc[2] += jv*wa.z; acc[3] += jv*wa.w;
                acc[4] += jv*wb.x; acc[5] += jv*wb.y; acc[6] += jv*wb.z; acc[7] += jv*wb.w;
            }
            #pragma unroll
            for (int c = 0; c < 8; ++c) sXP[c*512 + ks*128 + r] = acc[c];
            __syncthreads();
            u64 key[2]; float exv[2];
            #pragma unroll
            for (int i = 0; i < 2; ++i){
                int u = tid + i*512;
                int c = u >> 7, r2 = u & 127;
                const float* q = sXP + c*512 + r2;
                float lg = q[0] + q[128] + q[256] + q[384];
                exv[i] = expf(lg);
                int col = bid*8 + c;
                bool force = sNEm[r2] >= 2;
                int idx; float va;
                if (col == 0){ idx = 1024; va = lg; }
                else { idx = col; va = force ? LOWV : lg; }
                key[i] = ((u64)fkey(va) << 32) | (unsigned)(2047 - idx);
            }
            __syncthreads();
            u64* kx = (u64*)sXP;
            float* exs = (float*)(kx + 1024);
            #pragma unroll
            for (int i = 0; i < 2; ++i){
                int u = tid + i*512;
                int c = u >> 7, r2 = u & 127;
                kx[c*128 + r2] = key[i];
                exs[c*128 + r2] = exv[i];
            }
            __syncthreads();
            if (tid < 128){
                u64 m = kx[tid]; float es = exs[tid];
                #pragma unroll
                for (int q = 1; q < 8; ++q){
                    u64 o = kx[q*128 + tid]; if (o > m) m = o;
                    es += exs[q*128 + tid];
                }
                atomicMax(&packedP[((size_t)s*128 + tid)*8], m);
                atomicAdd(&sumexpP[((size_t)s*128 + tid)*16], es);
            }
        }
        gsync(false, false);  // B2 (atomics are MALL-coherent; no fences)

        // ===== P3: tok gather + replica update (all) | LSTM pointwise | lazy enc-proj | scorer =====
        if (tid < 128){
            u64 pk = aload_u64(&packedP[((size_t)s*128 + tid)*8]);
            int tok = 2047 - (int)(unsigned)(pk & 0xffffffffu);
            int act = sAct[tid];
            int isb = (tok == 1024);
            sTok[tid] = tok;
            sUpd[tid] = act && !isb;
            int et = sEncT[tid], ne = sNEm[tid], act_n = act, adv = -1;
            if (act){
                et += isb;
                ne = isb ? 0 : ne + 1;
                act_n = (et < sLen[tid]) ? 1 : 0;
                if (isb && act_n) adv = et;
            }
            sAdv[tid] = adv;
            sAct[tid] = act_n; sEncT[tid] = et; sNEm[tid] = ne;
            if (bid == 255){
                int tok_out = 1024;
                if (act){
                    float val = funkey((unsigned)(pk >> 32));
                    float se = aload_f(&sumexpP[((size_t)s*128 + tid)*16]);
                    scReg += val - logf(se);
                    tok_out = (act_n || isb) ? tok : 1024;
                }
                out[(size_t)tid*48 + s] = (float)tok_out;
                if (s == 47) out[6144 + tid] = scReg;
            }
        }
        __syncthreads();
        if (bid < 160){
            int j = bid*4 + (tid >> 7), r = tid & 127;
            float h2;
            if (sUpd[r]){
                int tok = sTok[r];
                float4 ew = EWi4[(size_t)tok*640 + j];
                float gi = gT[(size_t)j*128 + r]          + ew.x;
                float gf = gT[(size_t)(640 + j)*128 + r]  + ew.y;
                float gg = gT[(size_t)(1280 + j)*128 + r] + ew.z;
                float go = gT[(size_t)(1920 + j)*128 + r] + ew.w;
                float cn = sigf(gf)*creg + sigf(gi)*tanhf(gg);
                h2 = tanhf(cn)*sigf(go);
                creg = cn;
            } else {
                h2 = hp[(size_t)j*128 + r];
            }
            hT[(size_t)w*81920 + (size_t)j*128 + r] = h2;
        } else if (ec0 >= 0){
            for (int r = wv; r < 128; r += 8){
                int t = sAdv[r];
                if (t < 0) continue;
                const float* er = enc + ((size_t)r*160 + t)*1024;
                float a[6] = {0,0,0,0,0,0};
                int k4 = lane*4;
                #pragma unroll
                for (int i = 0; i < 4; ++i){
                    int k = i*256 + k4;
                    float4 ev = *(const float4*)(er + k);
                    for (int cc = 0; cc < nc; ++cc){
                        float4 w4 = *(const float4*)(sWe + cc*1024 + k);
                        a[cc] += ev.x*w4.x + ev.y*w4.y + ev.z*w4.z + ev.w*w4.w;
                    }
                }
                for (int cc = 0; cc < nc; ++cc){
                    #pragma unroll
                    for (int off = 32; off; off >>= 1) a[cc] += __shfl_xor(a[cc], off, 64);
                    if (lane == 0) encPT[(size_t)(ec0+cc)*128 + r] = a[cc];
                }
            }
        }
        gsync(true, true);    // B3
    }
}

extern "C" void kernel_launch(void* const* d_in, const int* in_sizes, int n_in,
                              void* d_out, int out_size, void* d_ws, size_t ws_size,
                              hipStream_t stream) {
    const float* enc   = (const float*)d_in[0];
    const int*   lens  = (const int*)  d_in[1];
    const float* E     = (const float*)d_in[3];
    const float* Wi    = (const float*)d_in[4];
    const float* Wh    = (const float*)d_in[5];
    const float* bi    = (const float*)d_in[6];
    const float* bh    = (const float*)d_in[7];
    const float* Wenc  = (const float*)d_in[8];
    const float* Wpred = (const float*)d_in[9];
    const float* bj    = (const float*)d_in[10];
    const float* Wout  = (const float*)d_in[11];
    float* out = (float*)d_out;

    char* base = (char*)d_ws;
    size_t off = 0;
    auto carve = [&](size_t bytes) -> void* {
        void* pp = base + off;
        off += (bytes + 255) & ~(size_t)255;
        return pp;
    };
    float*  WT    = (float*)carve((size_t)3072*640*4);
    float*  WoutT = (float*)carve((size_t)1024*512*4);
    float*  WencT = (float*)carve((size_t)512*1024*4);
    float4* EWi4  = (float4*)carve((size_t)1024*640*16);
    float*  hT    = (float*)carve((size_t)2*640*128*4);
    float*  encPT = (float*)carve((size_t)512*128*4);
    float*  jointT= (float*)carve((size_t)512*128*4);
    float*  gT    = (float*)carve((size_t)2560*128*4);
    u64*    packedP = (u64*)carve((size_t)48*128*8*8);    // stride 8 u64 (64B line per row)
    float*  sumexpP = (float*)carve((size_t)48*128*16*4); // stride 16 f32 (64B line per row)
    int*    cntZ  = (int*)carve(288*4);
    (void)ws_size; (void)in_sizes; (void)n_in; (void)out_size;

    k_tr <<<736,  256, 0, stream>>>(Wh, Wpred, Wout, Wenc, WT, WoutT, WencT, cntZ);
    k_ewi<<<1280, 256, 0, stream>>>(E, Wi, bi, bh, EWi4);
    mega <<<NBLK, 512, 0, stream>>>(enc, lens, bj, WT, WoutT, WencT, EWi4,
                                    hT, encPT, jointT, gT, packedP, sumexpP, cntZ, out);
}

// Round 9
// 2625.896 us; speedup vs baseline: 3.0555x; 1.4811x over previous
//
#include <hip/hip_runtime.h>

#define LOWV (-10000.0f)
#define NBLK 256
typedef unsigned long long u64;

__device__ __forceinline__ float sigf(float x){ return 1.0f/(1.0f+expf(-x)); }
__device__ __forceinline__ unsigned fkey(float f){
    unsigned u = __float_as_uint(f);
    return (u & 0x80000000u) ? ~u : (u | 0x80000000u);
}
__device__ __forceinline__ float funkey(unsigned k){
    unsigned u = (k & 0x80000000u) ? (k ^ 0x80000000u) : ~k;
    return __uint_as_float(u);
}
__device__ __forceinline__ int   aload_i (const int* p){ return __hip_atomic_load(p, __ATOMIC_RELAXED, __HIP_MEMORY_SCOPE_AGENT); }
__device__ __forceinline__ float aload_f (const float* p){ return __hip_atomic_load(p, __ATOMIC_RELAXED, __HIP_MEMORY_SCOPE_AGENT); }
__device__ __forceinline__ u64   aload_u64(const u64* p){ return __hip_atomic_load(p, __ATOMIC_RELAXED, __HIP_MEMORY_SCOPE_AGENT); }
__device__ __forceinline__ void  astore_i(int* p, int v){ __hip_atomic_store(p, v, __ATOMIC_RELAXED, __HIP_MEMORY_SCOPE_AGENT); }
__device__ __forceinline__ void  astore_f(float* p, float v){ __hip_atomic_store(p, v, __ATOMIC_RELAXED, __HIP_MEMORY_SCOPE_AGENT); }
__device__ __forceinline__ void  astore_u64(u64* p, u64 v){ __hip_atomic_store(p, v, __ATOMIC_RELAXED, __HIP_MEMORY_SCOPE_AGENT); }
// bypass (MALL-coherent) float/float2 accessors
__device__ __forceinline__ float bload(const float* p){ return aload_f(p); }
__device__ __forceinline__ void  bstore(float* p, float v){ astore_f(p, v); }
__device__ __forceinline__ float2 bload2(const float* p){
    union { u64 u; float2 f; } c;
    c.u = aload_u64((const u64*)p);
    return c.f;
}
__device__ __forceinline__ void bstore2(float* p, float2 v){
    union { u64 u; float2 f; } c; c.f = v;
    astore_u64((u64*)p, c.u);
}

// ---------- transposes: WT[3072][640] = [Wh|Wpred]^T, WoutT[1024][512], WencT[512][1024] ----------
__global__ __launch_bounds__(256) void k_tr(const float* __restrict__ Wh, const float* __restrict__ Wpred,
        const float* __restrict__ Wout, const float* __restrict__ Wenc,
        float* __restrict__ WT, float* __restrict__ WoutT, float* __restrict__ WencT,
        int* __restrict__ cntZ){
    if (blockIdx.x == 0){ for (int i = threadIdx.x; i < 544; i += 256) cntZ[i] = 0; }
    __shared__ float t[64][65];
    int b = blockIdx.x;
    const float* in; float* outp; int R, C, tr, tc, doff;
    if (b < 400)      { in=Wh;    outp=WT;    R=640;  C=2560; tr=b/40;        tc=b%40;        doff=0; }
    else if (b < 480) { b-=400; in=Wpred; outp=WT;    R=640;  C=512;  tr=b/8;  tc=b%8;  doff=2560; }
    else if (b < 608) { b-=480; in=Wout;  outp=WoutT; R=512;  C=1024; tr=b>>4; tc=b&15; doff=0; }
    else              { b-=608; in=Wenc;  outp=WencT; R=1024; C=512;  tr=b/8;  tc=b%8;  doff=0; }
    int tx = threadIdx.x & 63, ty0 = threadIdx.x >> 6;
    #pragma unroll
    for (int i = 0; i < 16; ++i){
        int row = i*4 + ty0;
        t[row][tx] = in[(size_t)(tr*64 + row)*C + tc*64 + tx];
    }
    __syncthreads();
    #pragma unroll
    for (int i = 0; i < 16; ++i){
        int row = i*4 + ty0;
        outp[(size_t)(doff + tc*64 + row)*R + tr*64 + tx] = t[tx][row];
    }
}

// ---------- EWi4[v*640+j] = float4 gates of E@Wi + bi + bh ----------
__global__ __launch_bounds__(256) void k_ewi(const float* __restrict__ E, const float* __restrict__ Wi,
        const float* __restrict__ bi, const float* __restrict__ bh, float4* __restrict__ EWi4){
    int tid = threadIdx.x, lane = tid & 63, wvv = tid >> 6;
    int vb = blockIdx.x / 10, jb = blockIdx.x % 10;   // 1280 blocks
    int j = jb*64 + lane;
    int v0 = vb*8 + wvv*2;
    float acc[2][4];
    #pragma unroll
    for (int i=0;i<2;++i)
        #pragma unroll
        for (int g=0;g<4;++g) acc[i][g] = 0.f;
    for (int k0 = 0; k0 < 512; k0 += 4){
        float ev[2][4];
        #pragma unroll
        for (int i=0;i<2;++i) *(float4*)ev[i] = *(const float4*)(E + (size_t)(v0+i)*512 + k0);
        #pragma unroll
        for (int kk=0;kk<4;++kk){
            const float* wr = Wi + (size_t)(k0+kk)*2560 + j;
            float w0 = wr[0], w1 = wr[640], w2 = wr[1280], w3 = wr[1920];
            #pragma unroll
            for (int i=0;i<2;++i){
                acc[i][0] += ev[i][kk]*w0; acc[i][1] += ev[i][kk]*w1;
                acc[i][2] += ev[i][kk]*w2; acc[i][3] += ev[i][kk]*w3;
            }
        }
    }
    float b0 = bi[j] + bh[j], b1 = bi[640+j] + bh[640+j];
    float b2 = bi[1280+j] + bh[1280+j], b3 = bi[1920+j] + bh[1920+j];
    #pragma unroll
    for (int i=0;i<2;++i)
        EWi4[(size_t)(v0+i)*640 + j] = make_float4(acc[i][0]+b0, acc[i][1]+b1, acc[i][2]+b2, acc[i][3]+b3);
}

// ---------- persistent decode kernel: 256 blocks x 512 threads, 1 block/CU, FENCE-FREE ----------
__global__ __launch_bounds__(512, 2) void mega(
    const float* __restrict__ enc, const int* __restrict__ lens, const float* __restrict__ bj,
    const float* __restrict__ WT, const float* __restrict__ WoutT, const float* __restrict__ WencT,
    const float4* __restrict__ EWi4,
    float* __restrict__ hT, float* __restrict__ encPT, float* __restrict__ jointT, float* __restrict__ gT,
    u64* __restrict__ packedP, float* __restrict__ sumexpP,
    int* __restrict__ cntZ, float* __restrict__ out)
{
    __shared__ float sW[12*640];                         // P1 weight slice [k][12]
    __shared__ __align__(16) float sXP[12*8*128];        // partials; P2 reduce aliases
    __shared__ float sB[8*512];                          // P2 Wout cols [k][8] (blocks 0..127)
    __shared__ float sWe[6*1024];                        // enc-proj cols (blocks 160..245)
    __shared__ float sBJ12[12];
    __shared__ int sAct[128], sEncT[128], sNEm[128], sLen[128];
    __shared__ int sTok[128], sUpd[128], sAdv[128];

    const int bid = blockIdx.x, tid = threadIdx.x, lane = tid & 63, wv = tid >> 6;
    int ep = 0;
    float creg = 0.f, scReg = 0.f;

    // fence-free barrier: bypass stores retire at MALL by vmcnt(0); no wbl2 / no inv anywhere
    auto gsync = [&](){
        asm volatile("s_waitcnt vmcnt(0)" ::: "memory");   // every wave drains its own stores
        __syncthreads();
        ++ep;
        if (tid == 0){
            __hip_atomic_fetch_add(&cntZ[(bid & 15)*16], 1, __ATOMIC_RELAXED, __HIP_MEMORY_SCOPE_AGENT);
            if (bid < 16){
                while (__hip_atomic_load(&cntZ[bid*16], __ATOMIC_RELAXED, __HIP_MEMORY_SCOPE_AGENT) < ep*16)
                    __builtin_amdgcn_s_sleep(2);
                __hip_atomic_fetch_add(&cntZ[256], 1, __ATOMIC_RELAXED, __HIP_MEMORY_SCOPE_AGENT);
            }
            if (bid == 0){
                while (__hip_atomic_load(&cntZ[256], __ATOMIC_RELAXED, __HIP_MEMORY_SCOPE_AGENT) < ep*16)
                    __builtin_amdgcn_s_sleep(2);
                #pragma unroll
                for (int i = 0; i < 16; ++i)
                    __hip_atomic_store(&cntZ[272 + i*16], ep, __ATOMIC_RELAXED, __HIP_MEMORY_SCOPE_AGENT);
            } else {
                while (__hip_atomic_load(&cntZ[272 + (bid & 15)*16], __ATOMIC_RELAXED, __HIP_MEMORY_SCOPE_AGENT) < ep)
                    __builtin_amdgcn_s_sleep(4);
            }
        }
        __syncthreads();
    };

    // ---- weight staging (normal cached loads; read-only data stays L2-hot forever) ----
    for (int i = tid; i < 7680; i += 512){
        int c = i / 640, k = i - c*640;
        sW[k*12 + c] = WT[(size_t)(bid*12 + c)*640 + k];
    }
    if (bid < 128){
        for (int i = tid; i < 4096; i += 512){
            int k = i >> 3, c = i & 7;
            sB[k*8 + c] = WoutT[(size_t)(bid*8 + c)*512 + k];
        }
    }
    const int ec0 = (bid >= 160 && bid < 246) ? (bid-160)*6 : -1;
    const int nc  = (ec0 >= 0) ? ((512 - ec0) < 6 ? (512 - ec0) : 6) : 0;
    if (ec0 >= 0){
        for (int i = tid; i < 6144; i += 512){
            int cc = i >> 10, k = i & 1023;
            if (cc < nc) sWe[i] = WencT[(size_t)(ec0+cc)*1024 + k];
        }
    }
    if (tid < 12){
        int col = bid*12 + tid;
        sBJ12[tid] = (col >= 2560) ? bj[col - 2560] : 0.f;
    }
    if (tid < 128){
        sAct[tid] = 1; sEncT[tid] = 0; sNEm[tid] = 0; sLen[tid] = lens[tid];
    }
    __syncthreads();

    // ---- prologue (all cross-block writes via bypass stores) ----
    for (int i = tid; i < 24; i += 512){
        int idx = bid*24 + i;                  // 256*24 = 6144 = 48*128
        astore_u64(&packedP[(size_t)idx*8], 0ull);
        astore_f(&sumexpP[(size_t)idx*16], 0.f);
    }
    if (bid < 160){
        int j = bid*4 + (tid >> 7), r = tid & 127;
        float4 e0 = EWi4[j];
        float c0v = sigf(e0.x)*tanhf(e0.z);
        creg = c0v;
        bstore(&hT[(size_t)j*128 + r], tanhf(c0v)*sigf(e0.w));
    }
    if (ec0 >= 0){
        for (int r = wv; r < 128; r += 8){
            const float* er = enc + (size_t)r*160*1024;   // frame 0
            float a[6] = {0,0,0,0,0,0};
            int k4 = lane*4;
            #pragma unroll
            for (int i = 0; i < 4; ++i){
                int k = i*256 + k4;
                float4 ev = *(const float4*)(er + k);
                for (int cc = 0; cc < nc; ++cc){
                    float4 w4 = *(const float4*)(sWe + cc*1024 + k);
                    a[cc] += ev.x*w4.x + ev.y*w4.y + ev.z*w4.z + ev.w*w4.w;
                }
            }
            for (int cc = 0; cc < nc; ++cc){
                #pragma unroll
                for (int off = 32; off; off >>= 1) a[cc] += __shfl_xor(a[cc], off, 64);
                if (lane == 0) bstore(&encPT[(size_t)(ec0+cc)*128 + r], a[cc]);
            }
        }
    }
    gsync();   // B0

    for (int s = 0; s < 48; ++s){
        const int p = s & 1, w = 1 - p;
        const float* hp = hT + (size_t)p*81920;

        // ===== P1: flat GEMV 3072 cols, 12 cols/block; wave = 80-k slice, lane = 2 rows =====
        {
            float acc[24];
            #pragma unroll
            for (int c = 0; c < 24; ++c) acc[c] = 0.f;
            const float* hc = hp + 2*lane;
            int k0 = wv*80;
            #pragma unroll 8
            for (int k = k0; k < k0 + 80; ++k){
                float2 h2 = bload2(hc + (size_t)k*128);
                const float* wk = sW + k*12;
                float4 wa = *(const float4*)(wk);
                float4 wb = *(const float4*)(wk + 4);
                float4 wc = *(const float4*)(wk + 8);
                acc[0]  += h2.x*wa.x; acc[1]  += h2.y*wa.x;
                acc[2]  += h2.x*wa.y; acc[3]  += h2.y*wa.y;
                acc[4]  += h2.x*wa.z; acc[5]  += h2.y*wa.z;
                acc[6]  += h2.x*wa.w; acc[7]  += h2.y*wa.w;
                acc[8]  += h2.x*wb.x; acc[9]  += h2.y*wb.x;
                acc[10] += h2.x*wb.y; acc[11] += h2.y*wb.y;
                acc[12] += h2.x*wb.z; acc[13] += h2.y*wb.z;
                acc[14] += h2.x*wb.w; acc[15] += h2.y*wb.w;
                acc[16] += h2.x*wc.x; acc[17] += h2.y*wc.x;
                acc[18] += h2.x*wc.y; acc[19] += h2.y*wc.y;
                acc[20] += h2.x*wc.z; acc[21] += h2.y*wc.z;
                acc[22] += h2.x*wc.w; acc[23] += h2.y*wc.w;
            }
            float2* sX2 = (float2*)sXP;
            #pragma unroll
            for (int c = 0; c < 12; ++c)
                sX2[c*512 + wv*64 + lane] = make_float2(acc[2*c], acc[2*c+1]);
        }
        __syncthreads();
        {
            float2* sX2 = (float2*)sXP;
            for (int u = tid; u < 768; u += 512){
                int c = u >> 6, l = u & 63;
                float vx = 0.f, vy = 0.f;
                #pragma unroll
                for (int ks = 0; ks < 8; ++ks){
                    float2 q = sX2[c*512 + ks*64 + l];
                    vx += q.x; vy += q.y;
                }
                int col = bid*12 + c;
                if (col < 2560){
                    bstore2(&gT[(size_t)col*128 + 2*l], make_float2(vx, vy));
                } else {
                    int cj = col - 2560;
                    float2 e = bload2(&encPT[(size_t)cj*128 + 2*l]);
                    float bjv = sBJ12[c];
                    bstore2(&jointT[(size_t)cj*128 + 2*l],
                            make_float2(tanhf(vx + e.x + bjv), tanhf(vy + e.y + bjv)));
                }
            }
        }
        gsync();   // B1

        // ===== P2: logits 8 cols/block (blocks 0..127); wave = 64-k slice, lane = 2 rows =====
        if (bid < 128){
            float acc[16];
            #pragma unroll
            for (int c = 0; c < 16; ++c) acc[c] = 0.f;
            const float* jc = jointT + 2*lane;
            int k0 = wv*64;
            #pragma unroll 8
            for (int k = k0; k < k0 + 64; ++k){
                float2 j2 = bload2(jc + (size_t)k*128);
                const float* wk = sB + k*8;
                float4 wa = *(const float4*)(wk);
                float4 wb = *(const float4*)(wk + 4);
                acc[0]  += j2.x*wa.x; acc[1]  += j2.y*wa.x;
                acc[2]  += j2.x*wa.y; acc[3]  += j2.y*wa.y;
                acc[4]  += j2.x*wa.z; acc[5]  += j2.y*wa.z;
                acc[6]  += j2.x*wa.w; acc[7]  += j2.y*wa.w;
                acc[8]  += j2.x*wb.x; acc[9]  += j2.y*wb.x;
                acc[10] += j2.x*wb.y; acc[11] += j2.y*wb.y;
                acc[12] += j2.x*wb.z; acc[13] += j2.y*wb.z;
                acc[14] += j2.x*wb.w; acc[15] += j2.y*wb.w;
            }
            float2* sX2 = (float2*)sXP;
            #pragma unroll
            for (int c = 0; c < 8; ++c)
                sX2[c*512 + wv*64 + lane] = make_float2(acc[2*c], acc[2*c+1]);
            __syncthreads();
            u64 key[2]; float exv[2];
            #pragma unroll
            for (int i = 0; i < 2; ++i){
                int u = tid + i*512;
                int c = u >> 7, r2 = u & 127;
                float lg = 0.f;
                #pragma unroll
                for (int ks = 0; ks < 8; ++ks) lg += sXP[c*1024 + ks*128 + r2];
                exv[i] = expf(lg);
                int col = bid*8 + c;
                bool force = sNEm[r2] >= 2;
                int idx; float va;
                if (col == 0){ idx = 1024; va = lg; }
                else { idx = col; va = force ? LOWV : lg; }
                key[i] = ((u64)fkey(va) << 32) | (unsigned)(2047 - idx);
            }
            __syncthreads();
            u64* kx = (u64*)sXP;
            float* exs = (float*)(kx + 1024);
            #pragma unroll
            for (int i = 0; i < 2; ++i){
                int u = tid + i*512;
                int c = u >> 7, r2 = u & 127;
                kx[c*128 + r2] = key[i];
                exs[c*128 + r2] = exv[i];
            }
            __syncthreads();
            if (tid < 128){
                u64 m = kx[tid]; float es = exs[tid];
                #pragma unroll
                for (int q = 1; q < 8; ++q){
                    u64 o = kx[q*128 + tid]; if (o > m) m = o;
                    es += exs[q*128 + tid];
                }
                atomicMax(&packedP[((size_t)s*128 + tid)*8], m);
                atomicAdd(&sumexpP[((size_t)s*128 + tid)*16], es);
            }
        }
        gsync();   // B2

        // ===== P3: tok gather + replicated state | LSTM pointwise | lazy enc-proj | scorer =====
        if (tid < 128){
            u64 pk = aload_u64(&packedP[((size_t)s*128 + tid)*8]);
            int tok = 2047 - (int)(unsigned)(pk & 0xffffffffu);
            int act = sAct[tid];
            int isb = (tok == 1024);
            sTok[tid] = tok;
            sUpd[tid] = act && !isb;
            int et = sEncT[tid], ne = sNEm[tid], act_n = act, adv = -1;
            if (act){
                et += isb;
                ne = isb ? 0 : ne + 1;
                act_n = (et < sLen[tid]) ? 1 : 0;
                if (isb && act_n) adv = et;
            }
            sAdv[tid] = adv;
            sAct[tid] = act_n; sEncT[tid] = et; sNEm[tid] = ne;
            if (bid == 255){
                int tok_out = 1024;
                if (act){
                    float val = funkey((unsigned)(pk >> 32));
                    float se = aload_f(&sumexpP[((size_t)s*128 + tid)*16]);
                    scReg += val - logf(se);
                    tok_out = (act_n || isb) ? tok : 1024;
                }
                out[(size_t)tid*48 + s] = (float)tok_out;
                if (s == 47) out[6144 + tid] = scReg;
            }
        }
        __syncthreads();
        if (bid < 160){
            int j = bid*4 + (tid >> 7), r = tid & 127;
            float h2;
            if (sUpd[r]){
                int tok = sTok[r];
                float4 ew = EWi4[(size_t)tok*640 + j];            // cached, L2-hot
                float gi = bload(&gT[(size_t)j*128 + r])          + ew.x;
                float gf = bload(&gT[(size_t)(640 + j)*128 + r])  + ew.y;
                float gg = bload(&gT[(size_t)(1280 + j)*128 + r]) + ew.z;
                float go = bload(&gT[(size_t)(1920 + j)*128 + r]) + ew.w;
                float cn = sigf(gf)*creg + sigf(gi)*tanhf(gg);
                h2 = tanhf(cn)*sigf(go);
                creg = cn;
            } else {
                h2 = bload(&hp[(size_t)j*128 + r]);
            }
            bstore(&hT[(size_t)w*81920 + (size_t)j*128 + r], h2);
        } else if (ec0 >= 0){
            for (int r = wv; r < 128; r += 8){
                int t = sAdv[r];
                if (t < 0) continue;
                const float* er = enc + ((size_t)r*160 + t)*1024;   // cached, L2-hot
                float a[6] = {0,0,0,0,0,0};
                int k4 = lane*4;
                #pragma unroll
                for (int i = 0; i < 4; ++i){
                    int k = i*256 + k4;
                    float4 ev = *(const float4*)(er + k);
                    for (int cc = 0; cc < nc; ++cc){
                        float4 w4 = *(const float4*)(sWe + cc*1024 + k);
                        a[cc] += ev.x*w4.x + ev.y*w4.y + ev.z*w4.z + ev.w*w4.w;
                    }
                }
                for (int cc = 0; cc < nc; ++cc){
                    #pragma unroll
                    for (int off = 32; off; off >>= 1) a[cc] += __shfl_xor(a[cc], off, 64);
                    if (lane == 0) bstore(&encPT[(size_t)(ec0+cc)*128 + r], a[cc]);
                }
            }
        }
        gsync();    // B3
    }
}

extern "C" void kernel_launch(void* const* d_in, const int* in_sizes, int n_in,
                              void* d_out, int out_size, void* d_ws, size_t ws_size,
                              hipStream_t stream) {
    const float* enc   = (const float*)d_in[0];
    const int*   lens  = (const int*)  d_in[1];
    const float* E     = (const float*)d_in[3];
    const float* Wi    = (const float*)d_in[4];
    const float* Wh    = (const float*)d_in[5];
    const float* bi    = (const float*)d_in[6];
    const float* bh    = (const float*)d_in[7];
    const float* Wenc  = (const float*)d_in[8];
    const float* Wpred = (const float*)d_in[9];
    const float* bj    = (const float*)d_in[10];
    const float* Wout  = (const float*)d_in[11];
    float* out = (float*)d_out;

    char* base = (char*)d_ws;
    size_t off = 0;
    auto carve = [&](size_t bytes) -> void* {
        void* pp = base + off;
        off += (bytes + 255) & ~(size_t)255;
        return pp;
    };
    float*  WT    = (float*)carve((size_t)3072*640*4);
    float*  WoutT = (float*)carve((size_t)1024*512*4);
    float*  WencT = (float*)carve((size_t)512*1024*4);
    float4* EWi4  = (float4*)carve((size_t)1024*640*16);
    float*  hT    = (float*)carve((size_t)2*640*128*4);
    float*  encPT = (float*)carve((size_t)512*128*4);
    float*  jointT= (float*)carve((size_t)512*128*4);
    float*  gT    = (float*)carve((size_t)2560*128*4);
    u64*    packedP = (u64*)carve((size_t)48*128*8*8);    // 64B line per row
    float*  sumexpP = (float*)carve((size_t)48*128*16*4); // 64B line per row
    int*    cntZ  = (int*)carve(544*4);
    (void)ws_size; (void)in_sizes; (void)n_in; (void)out_size;

    k_tr <<<736,  256, 0, stream>>>(Wh, Wpred, Wout, Wenc, WT, WoutT, WencT, cntZ);
    k_ewi<<<1280, 256, 0, stream>>>(E, Wi, bi, bh, EWi4);
    mega <<<NBLK, 512, 0, stream>>>(enc, lens, bj, WT, WoutT, WencT, EWi4,
                                    hT, encPT, jointT, gT, packedP, sumexpP, cntZ, out);
}